// Round 2
// baseline (385.496 us; speedup 1.0000x reference)
//
#include <hip/hip_runtime.h>
#include <math.h>

#define BB 32
#define HH 128
#define SS 8192

typedef __attribute__((ext_vector_type(8))) short bf8;
typedef __attribute__((ext_vector_type(4))) float f4;

static __device__ __forceinline__ unsigned short f2bf(float x) {
  union { float f; unsigned int u; } c; c.f = x;
  unsigned int r = c.u + 0x7FFFu + ((c.u >> 16) & 1u);  // RNE
  return (unsigned short)(r >> 16);
}

// X-tile swizzle: varies per-lane for BOTH the staging writes (srow step 4)
// and the fragment reads (srow step 1). chunk_phys = chunk_log ^ XSWZ(srow).
#define XSWZ(r) ((((r) >> 2) ^ (r)) & 7)

// ---------------- prep: bias[b][h] = W[h, 256:384] . dec[b]; Abf = bf16(W[:,0:256]) ----------------
__global__ __launch_bounds__(256) void prep_kernel(
    const float* __restrict__ W, const float* __restrict__ dec,
    unsigned short* __restrict__ Abf, float* __restrict__ bias) {
  const int b = blockIdx.x;
  const int tid = threadIdx.x;
  if (tid < HH) {
    const float* wr = W + (size_t)tid * 384 + 256;
    const float* db = dec + (size_t)b * HH;
    float acc = 0.f;
    #pragma unroll 8
    for (int j = 0; j < HH; ++j) acc += wr[j] * db[j];
    bias[b * HH + tid] = acc;
  }
  if (b == 0) {
    #pragma unroll 4
    for (int idx = tid; idx < HH * 256; idx += 256) {
      int h = idx >> 8, k = idx & 255;
      Abf[idx] = f2bf(W[h * 384 + k]);
    }
  }
}

// ---------------- main: scores[b][s] = sum_h v[h] * tanh(A@X + bias) ----------------
// Persistent streaming GEMM. Grid = 256 blocks (1/CU, 128KB LDS), 16 waves.
// Each block owns b = blockIdx>>3 and 4 s-strips of 256; A (128x256 bf16) staged
// to LDS once, then 16 chunk-iterations (4 strips x 4 k-chunks of 64) run in one
// continuous pipeline: loads for chunk t+2 issued before chunk t's MFMAs, so
// convWrite(t+1) waits vmcnt(4) on loads a full chunk-period old (never vmcnt(0)).
// X LDS tile [256 s][64 k] bf16, double-buffered, XSWZ chunk swizzle ->
// conflict-free ds_write_b64 staging AND ds_read_b128 fragments.
__global__ __launch_bounds__(1024, 4) void attn_main(
    const float* __restrict__ sta, const float* __restrict__ dyn,
    const unsigned short* __restrict__ Abf, const float* __restrict__ bias,
    const float* __restrict__ v, float* __restrict__ scores) {
  extern __shared__ __align__(16) unsigned short smem[];
  unsigned short* LA = smem;            // [128][256] bf16, 16B-chunk swizzled (64KB)
  unsigned short* LX = smem + 32768;    // 2 x [256 s][64 k] bf16, swizzled (2x32KB)

  const int tid  = threadIdx.x;
  const int l    = tid & 63;
  const int w    = tid >> 6;            // wave 0..15
  const int quad = l >> 4;
  const int n16  = l & 15;
  const int b       = blockIdx.x >> 3;
  const int sb_base = (blockIdx.x & 7) << 2;   // first strip index (of 32) for this block

  // staging thread mapping: this thread covers k_local kq..kq+3, s_local sl..sl+3
  const int kq = ((w >> 2) << 4) + (quad << 2);   // 0..60 step 4
  const int sl = ((w & 3) << 6) + (n16 << 2);     // 0..252 step 4
  const size_t xoff_b = (size_t)b * HH * SS;

  f4 g[2][4];                            // 2-deep register prefetch stages

  auto issueX = [&](int t, f4* gg) {     // chunk index t = strip*4 + c, c in 0..3
    const int c = t & 3;
    const float* base = (c < 2) ? sta : dyn;
    const float* p = base + xoff_b + (size_t)(((c & 1) << 6) + kq) * SS
                   + (((sb_base + (t >> 2)) << 8) + sl);
    #pragma unroll
    for (int j = 0; j < 4; ++j) gg[j] = *(const f4*)(p + (size_t)j * SS);
  };
  auto convWrite = [&](const f4* gg, int buf) {
    unsigned short* X = LX + (buf << 14);
    #pragma unroll
    for (int i = 0; i < 4; ++i) {
      const int srow = sl + i;
      ushort4 o;
      o.x = f2bf(gg[0][i]); o.y = f2bf(gg[1][i]);
      o.z = f2bf(gg[2][i]); o.w = f2bf(gg[3][i]);
      *(ushort4*)&X[(srow << 6) + ((((kq >> 3) ^ XSWZ(srow)) << 3) | (kq & 7))] = o;
    }
  };

  // ---- prologue: issue chunks 0,1; stage A; write chunk 0 ----
  issueX(0, g[0]);
  #pragma unroll
  for (int j = 0; j < 4; ++j) {          // A: 64KB, 16B chunks, phys ck = ck ^ (m&7)
    int gc = (j << 10) + tid;            // 0..4095 chunk id; m = gc>>5, ck = gc&31
    int m = gc >> 5, ck = gc & 31;
    bf8 val = *(const bf8*)(Abf + ((size_t)gc << 3));
    *(bf8*)&LA[(m << 8) + ((ck ^ (m & 7)) << 3)] = val;
  }
  issueX(1, g[1]);
  convWrite(g[0], 0);
  __syncthreads();

  f4 acc[8];
  #pragma unroll
  for (int mt = 0; mt < 8; ++mt) acc[mt] = (f4){0.f, 0.f, 0.f, 0.f};

  const int srow_f = (w << 4) + n16;     // this wave's B-fragment s row
  const int xrow = srow_f << 6;
  const int sswz = XSWZ(srow_f);
  const int aswz = n16 & 7;

  for (int strip = 0; strip < 4; ++strip) {
    #pragma unroll
    for (int c = 0; c < 4; ++c) {
      const int t = (strip << 2) + c;
      if (t + 2 < 16) issueX(t + 2, g[c & 1]);   // HBM stream 2 chunks ahead
      const unsigned short* X = LX + ((c & 1) << 14);
      bf8 bf0 = *(const bf8*)&X[xrow + ((quad ^ sswz) << 3)];         // ks=0
      bf8 bf1 = *(const bf8*)&X[xrow + (((4 + quad) ^ sswz) << 3)];   // ks=1
      #pragma unroll
      for (int mt = 0; mt < 8; ++mt) {
        const int arow = (mt << 4) + n16;
        bf8 a0 = *(const bf8*)&LA[(arow << 8) + ((((c << 3) + quad) ^ aswz) << 3)];
        acc[mt] = __builtin_amdgcn_mfma_f32_16x16x32_bf16(a0, bf0, acc[mt], 0, 0, 0);
        bf8 a1 = *(const bf8*)&LA[(arow << 8) + ((((c << 3) + 4 + quad) ^ aswz) << 3)];
        acc[mt] = __builtin_amdgcn_mfma_f32_16x16x32_bf16(a1, bf1, acc[mt], 0, 0, 0);
      }
      if (t + 1 < 16) convWrite(g[(c + 1) & 1], (c + 1) & 1);  // waits vmcnt(4)
      if (c == 3) {
        // epilogue for this strip: z = acc + bias[h]; part += v[h]*tanh(z)
        float part = 0.f;
        #pragma unroll
        for (int mt = 0; mt < 8; ++mt) {
          #pragma unroll
          for (int r = 0; r < 4; ++r) {
            const int h = (mt << 4) + (quad << 2) + r;   // C/D row = quad*4 + reg
            part += v[h] * tanhf(acc[mt][r] + bias[(b << 7) + h]);
            acc[mt][r] = 0.f;
          }
        }
        part += __shfl_xor(part, 16, 64);
        part += __shfl_xor(part, 32, 64);
        if (quad == 0)
          scores[((size_t)b << 13) + (((sb_base + strip) << 8) + srow_f)] = part;
      }
      __syncthreads();
    }
  }
}

// ---------------- softmax over s, in-place on d_out ----------------
__global__ __launch_bounds__(1024) void softmax_kernel(float* __restrict__ out) {
  const int b = blockIdx.x;
  const int tid = threadIdx.x;
  float* row = out + ((size_t)b << 13);
  float4 x0 = ((const float4*)row)[tid];
  float4 x1 = ((const float4*)row)[tid + 1024];
  float lmax = fmaxf(fmaxf(fmaxf(x0.x, x0.y), fmaxf(x0.z, x0.w)),
                     fmaxf(fmaxf(x1.x, x1.y), fmaxf(x1.z, x1.w)));
  __shared__ float red[17];
  #pragma unroll
  for (int o = 32; o >= 1; o >>= 1) lmax = fmaxf(lmax, __shfl_xor(lmax, o, 64));
  if ((tid & 63) == 0) red[tid >> 6] = lmax;
  __syncthreads();
  if (tid < 64) {
    float m = (tid < 16) ? red[tid] : -3.0e38f;
    #pragma unroll
    for (int o = 8; o >= 1; o >>= 1) m = fmaxf(m, __shfl_xor(m, o, 64));
    if (tid == 0) red[16] = m;
  }
  __syncthreads();
  const float gmax = red[16];
  float e[8];
  e[0] = expf(x0.x - gmax); e[1] = expf(x0.y - gmax);
  e[2] = expf(x0.z - gmax); e[3] = expf(x0.w - gmax);
  e[4] = expf(x1.x - gmax); e[5] = expf(x1.y - gmax);
  e[6] = expf(x1.z - gmax); e[7] = expf(x1.w - gmax);
  float ls = e[0] + e[1] + e[2] + e[3] + e[4] + e[5] + e[6] + e[7];
  #pragma unroll
  for (int o = 32; o >= 1; o >>= 1) ls += __shfl_xor(ls, o, 64);
  __syncthreads();   // gmax consumed; safe to reuse red
  if ((tid & 63) == 0) red[tid >> 6] = ls;
  __syncthreads();
  if (tid < 64) {
    float m = (tid < 16) ? red[tid] : 0.f;
    #pragma unroll
    for (int o = 8; o >= 1; o >>= 1) m += __shfl_xor(m, o, 64);
    if (tid == 0) red[16] = m;
  }
  __syncthreads();
  const float inv = 1.0f / red[16];
  float4 o0 = make_float4(e[0] * inv, e[1] * inv, e[2] * inv, e[3] * inv);
  float4 o1 = make_float4(e[4] * inv, e[5] * inv, e[6] * inv, e[7] * inv);
  ((float4*)row)[tid] = o0;
  ((float4*)row)[tid + 1024] = o1;
}

extern "C" void kernel_launch(void* const* d_in, const int* in_sizes, int n_in,
                              void* d_out, int out_size, void* d_ws, size_t ws_size,
                              hipStream_t stream) {
  const float* sta = (const float*)d_in[0];   // (32,128,8192)
  const float* dyn = (const float*)d_in[1];   // (32,128,8192)
  const float* dec = (const float*)d_in[2];   // (32,128)
  const float* v   = (const float*)d_in[3];   // (128)
  const float* W   = (const float*)d_in[4];   // (128,384)

  unsigned short* Abf = (unsigned short*)d_ws;             // 64 KB
  float* bias = (float*)((char*)d_ws + 128 * 256 * 2);     // 16 KB
  float* scores = (float*)d_out;                           // 1 MB, softmaxed in place

  static bool attr_done = false;
  if (!attr_done) {
    (void)hipFuncSetAttribute((const void*)attn_main,
                              hipFuncAttributeMaxDynamicSharedMemorySize, 131072);
    attr_done = true;
  }

  prep_kernel<<<BB, 256, 0, stream>>>(W, dec, Abf, bias);
  attn_main<<<BB * 8, 1024, 131072, stream>>>(sta, dyn, Abf, bias, v, scores);
  softmax_kernel<<<BB, 1024, 0, stream>>>(scores);
}

// Round 3
// 336.206 us; speedup vs baseline: 1.1466x; 1.1466x over previous
//
#include <hip/hip_runtime.h>
#include <math.h>

#define BB 32
#define HH 128
#define SS 8192

typedef __attribute__((ext_vector_type(8))) short bf8;
typedef __attribute__((ext_vector_type(4))) float f4;

static __device__ __forceinline__ unsigned short f2bf(float x) {
  union { float f; unsigned int u; } c; c.f = x;
  unsigned int r = c.u + 0x7FFFu + ((c.u >> 16) & 1u);  // RNE
  return (unsigned short)(r >> 16);
}

// X-tile swizzle: varies per-lane for BOTH the staging writes (srow step 4)
// and the fragment reads (srow step 1). chunk_phys = chunk_log ^ XSWZ(srow).
#define XSWZ(r) ((((r) >> 2) ^ (r)) & 7)

// ---------------- prep: bias[b][h] = W[h, 256:384] . dec[b]; Abf = bf16(W[:,0:256]) ----------------
__global__ __launch_bounds__(256) void prep_kernel(
    const float* __restrict__ W, const float* __restrict__ dec,
    unsigned short* __restrict__ Abf, float* __restrict__ bias) {
  const int b = blockIdx.x;
  const int tid = threadIdx.x;
  if (tid < HH) {
    const float* wr = W + (size_t)tid * 384 + 256;
    const float* db = dec + (size_t)b * HH;
    float acc = 0.f;
    #pragma unroll 8
    for (int j = 0; j < HH; ++j) acc += wr[j] * db[j];
    bias[b * HH + tid] = acc;
  }
  if (b == 0) {
    #pragma unroll 4
    for (int idx = tid; idx < HH * 256; idx += 256) {
      int h = idx >> 8, k = idx & 255;
      Abf[idx] = f2bf(W[h * 384 + k]);
    }
  }
}

// ---------------- main: scores[b][s] = sum_h v[h] * tanh(A@X + bias) ----------------
// Persistent streaming GEMM, 2-deep register prefetch with NAMED register stages
// (GA0..3 / GB0..3) driven by token-pasting macros so nothing is address-taken and
// every index is compile-time (round 2's pointer-passed stages went to scratch:
// WRITE_SIZE 1MB -> 62MB, dur 110 -> 186us).
// Grid = 256 blocks (1/CU, 128KB LDS), 16 waves. Block owns b = blk>>3 and 4
// s-strips of 256. A (128x256 bf16) staged once; 16 chunk-steps fully unrolled:
// STEP(t): issue chunk t+2 -> MFMAs on LDS buf t&1 -> convWrite chunk t+1 into
// buf (t+1)&1 (vmcnt(4): those loads are a full chunk-period old) -> barrier.
// X LDS tile [256 s][64 k] bf16 double-buffered, XSWZ chunk swizzle: write is
// 4 lanes/bank-pair (wave-write minimum) and read is 8 lanes/chunk over the
// 8-cycle b128 minimum -> conflict-free.
__global__ __launch_bounds__(1024, 4) void attn_main(
    const float* __restrict__ sta, const float* __restrict__ dyn,
    const unsigned short* __restrict__ Abf, const float* __restrict__ bias,
    const float* __restrict__ v, float* __restrict__ scores) {
  extern __shared__ __align__(16) unsigned short smem[];
  unsigned short* LA = smem;            // [128][256] bf16, 16B-chunk swizzled (64KB)
  unsigned short* LX = smem + 32768;    // 2 x [256 s][64 k] bf16, swizzled (2x32KB)

  const int tid  = threadIdx.x;
  const int l    = tid & 63;
  const int w    = tid >> 6;            // wave 0..15
  const int quad = l >> 4;
  const int n16  = l & 15;
  const int b       = blockIdx.x >> 3;
  const int sb_base = (blockIdx.x & 7) << 2;   // first strip (of 32) for this block

  // staging thread mapping: this thread covers k_local kq..kq+3, s_local sl..sl+3
  const int kq = ((w >> 2) << 4) + (quad << 2);   // 0..60 step 4
  const int sl = ((w & 3) << 6) + (n16 << 2);     // 0..252 step 4
  const size_t xoff_b = (size_t)b * HH * SS;

  f4 GA0, GA1, GA2, GA3;                // prefetch stage A (even chunks)
  f4 GB0, GB1, GB2, GB3;                // prefetch stage B (odd chunks)

#define ISSUE(t, G) do {                                                      \
    const float* base_ = (((t) & 3) < 2) ? sta : dyn;                         \
    const float* p_ = base_ + xoff_b + (size_t)((((t) & 1) << 6) + kq) * SS   \
                    + (((sb_base + ((t) >> 2)) << 8) + sl);                   \
    G##0 = *(const f4*)(p_);                                                  \
    G##1 = *(const f4*)(p_ + (size_t)SS);                                     \
    G##2 = *(const f4*)(p_ + 2 * (size_t)SS);                                 \
    G##3 = *(const f4*)(p_ + 3 * (size_t)SS);                                 \
  } while (0)

#define CW1(G, Xp, i) do {                                                    \
    const int srow_ = sl + (i);                                               \
    ushort4 o_;                                                               \
    o_.x = f2bf(G##0[(i)]); o_.y = f2bf(G##1[(i)]);                           \
    o_.z = f2bf(G##2[(i)]); o_.w = f2bf(G##3[(i)]);                           \
    *(ushort4*)&(Xp)[(srow_ << 6) +                                           \
        ((((kq >> 3) ^ XSWZ(srow_)) << 3) | (kq & 7))] = o_;                  \
  } while (0)

#define CONVWRITE(G, buf) do {                                                \
    unsigned short* Xp_ = LX + ((buf) << 14);                                 \
    CW1(G, Xp_, 0); CW1(G, Xp_, 1); CW1(G, Xp_, 2); CW1(G, Xp_, 3);           \
  } while (0)

#define MFMA_CHUNK(buf, c) do {                                               \
    const unsigned short* X_ = LX + ((buf) << 14);                            \
    bf8 bf0_ = *(const bf8*)&X_[xrow + ((quad ^ sswz) << 3)];                 \
    bf8 bf1_ = *(const bf8*)&X_[xrow + (((4 + quad) ^ sswz) << 3)];           \
    _Pragma("unroll")                                                         \
    for (int mt = 0; mt < 8; ++mt) {                                          \
      const int arow = (mt << 4) + n16;                                       \
      bf8 a0_ = *(const bf8*)&LA[(arow << 8) +                                \
                                 (((((c) << 3) + quad) ^ aswz) << 3)];        \
      acc[mt] = __builtin_amdgcn_mfma_f32_16x16x32_bf16(a0_, bf0_, acc[mt],   \
                                                        0, 0, 0);             \
      bf8 a1_ = *(const bf8*)&LA[(arow << 8) +                                \
                                 (((((c) << 3) + 4 + quad) ^ aswz) << 3)];    \
      acc[mt] = __builtin_amdgcn_mfma_f32_16x16x32_bf16(a1_, bf1_, acc[mt],   \
                                                        0, 0, 0);             \
    }                                                                         \
  } while (0)

#define EPILOGUE(strip) do {                                                  \
    float part_ = 0.f;                                                        \
    _Pragma("unroll")                                                         \
    for (int mt = 0; mt < 8; ++mt) {                                          \
      _Pragma("unroll")                                                       \
      for (int r = 0; r < 4; ++r) {                                           \
        const int h_ = (mt << 4) + (quad << 2) + r;                           \
        part_ += v[h_] * tanhf(acc[mt][r] + bias[(b << 7) + h_]);             \
        acc[mt][r] = 0.f;                                                     \
      }                                                                       \
    }                                                                         \
    part_ += __shfl_xor(part_, 16, 64);                                       \
    part_ += __shfl_xor(part_, 32, 64);                                       \
    if (quad == 0)                                                            \
      scores[((size_t)b << 13) +                                              \
             (((sb_base + (strip)) << 8) + srow_f)] = part_;                  \
  } while (0)

#define STEP(t, GCUR, GNXT) do {                                              \
    if ((t) + 2 < 16) ISSUE((t) + 2, GCUR);                                   \
    MFMA_CHUNK((t) & 1, (t) & 3);                                             \
    if ((t) + 1 < 16) CONVWRITE(GNXT, ((t) + 1) & 1);                         \
    if (((t) & 3) == 3) EPILOGUE((t) >> 2);                                   \
    __syncthreads();                                                          \
  } while (0)

  // ---- prologue: issue chunks 0,1; stage A; write chunk 0 ----
  ISSUE(0, GA);
  #pragma unroll
  for (int j = 0; j < 4; ++j) {          // A: 64KB, 16B chunks, phys ck = ck ^ (m&7)
    int gc = (j << 10) + tid;            // 0..4095 chunk id; m = gc>>5, ck = gc&31
    int m = gc >> 5, ck = gc & 31;
    bf8 val = *(const bf8*)(Abf + ((size_t)gc << 3));
    *(bf8*)&LA[(m << 8) + ((ck ^ (m & 7)) << 3)] = val;
  }
  ISSUE(1, GB);
  CONVWRITE(GA, 0);
  __syncthreads();

  f4 acc[8];
  #pragma unroll
  for (int mt = 0; mt < 8; ++mt) acc[mt] = (f4){0.f, 0.f, 0.f, 0.f};

  const int srow_f = (w << 4) + n16;     // this wave's B-fragment s row
  const int xrow = srow_f << 6;
  const int sswz = XSWZ(srow_f);
  const int aswz = n16 & 7;

  STEP(0, GA, GB);   STEP(1, GB, GA);   STEP(2, GA, GB);   STEP(3, GB, GA);
  STEP(4, GA, GB);   STEP(5, GB, GA);   STEP(6, GA, GB);   STEP(7, GB, GA);
  STEP(8, GA, GB);   STEP(9, GB, GA);   STEP(10, GA, GB);  STEP(11, GB, GA);
  STEP(12, GA, GB);  STEP(13, GB, GA);  STEP(14, GA, GB);  STEP(15, GB, GA);
}

// ---------------- softmax over s, in-place on d_out ----------------
__global__ __launch_bounds__(1024) void softmax_kernel(float* __restrict__ out) {
  const int b = blockIdx.x;
  const int tid = threadIdx.x;
  float* row = out + ((size_t)b << 13);
  float4 x0 = ((const float4*)row)[tid];
  float4 x1 = ((const float4*)row)[tid + 1024];
  float lmax = fmaxf(fmaxf(fmaxf(x0.x, x0.y), fmaxf(x0.z, x0.w)),
                     fmaxf(fmaxf(x1.x, x1.y), fmaxf(x1.z, x1.w)));
  __shared__ float red[17];
  #pragma unroll
  for (int o = 32; o >= 1; o >>= 1) lmax = fmaxf(lmax, __shfl_xor(lmax, o, 64));
  if ((tid & 63) == 0) red[tid >> 6] = lmax;
  __syncthreads();
  if (tid < 64) {
    float m = (tid < 16) ? red[tid] : -3.0e38f;
    #pragma unroll
    for (int o = 8; o >= 1; o >>= 1) m = fmaxf(m, __shfl_xor(m, o, 64));
    if (tid == 0) red[16] = m;
  }
  __syncthreads();
  const float gmax = red[16];
  float e[8];
  e[0] = expf(x0.x - gmax); e[1] = expf(x0.y - gmax);
  e[2] = expf(x0.z - gmax); e[3] = expf(x0.w - gmax);
  e[4] = expf(x1.x - gmax); e[5] = expf(x1.y - gmax);
  e[6] = expf(x1.z - gmax); e[7] = expf(x1.w - gmax);
  float ls = e[0] + e[1] + e[2] + e[3] + e[4] + e[5] + e[6] + e[7];
  #pragma unroll
  for (int o = 32; o >= 1; o >>= 1) ls += __shfl_xor(ls, o, 64);
  __syncthreads();   // gmax consumed; safe to reuse red
  if ((tid & 63) == 0) red[tid >> 6] = ls;
  __syncthreads();
  if (tid < 64) {
    float m = (tid < 16) ? red[tid] : 0.f;
    #pragma unroll
    for (int o = 8; o >= 1; o >>= 1) m += __shfl_xor(m, o, 64);
    if (tid == 0) red[16] = m;
  }
  __syncthreads();
  const float inv = 1.0f / red[16];
  float4 o0 = make_float4(e[0] * inv, e[1] * inv, e[2] * inv, e[3] * inv);
  float4 o1 = make_float4(e[4] * inv, e[5] * inv, e[6] * inv, e[7] * inv);
  ((float4*)row)[tid] = o0;
  ((float4*)row)[tid + 1024] = o1;
}

extern "C" void kernel_launch(void* const* d_in, const int* in_sizes, int n_in,
                              void* d_out, int out_size, void* d_ws, size_t ws_size,
                              hipStream_t stream) {
  const float* sta = (const float*)d_in[0];   // (32,128,8192)
  const float* dyn = (const float*)d_in[1];   // (32,128,8192)
  const float* dec = (const float*)d_in[2];   // (32,128)
  const float* v   = (const float*)d_in[3];   // (128)
  const float* W   = (const float*)d_in[4];   // (128,384)

  unsigned short* Abf = (unsigned short*)d_ws;             // 64 KB
  float* bias = (float*)((char*)d_ws + 128 * 256 * 2);     // 16 KB
  float* scores = (float*)d_out;                           // 1 MB, softmaxed in place

  static bool attr_done = false;
  if (!attr_done) {
    (void)hipFuncSetAttribute((const void*)attn_main,
                              hipFuncAttributeMaxDynamicSharedMemorySize, 131072);
    attr_done = true;
  }

  prep_kernel<<<BB, 256, 0, stream>>>(W, dec, Abf, bias);
  attn_main<<<BB * 8, 1024, 131072, stream>>>(sta, dyn, Abf, bias, v, scores);
  softmax_kernel<<<BB, 1024, 0, stream>>>(scores);
}